// Round 9
// baseline (574.891 us; speedup 1.0000x reference)
//
#include <hip/hip_runtime.h>
#include <hip/hip_bf16.h>
#include <hip/hip_fp16.h>

#define N_NODES 50000
#define N_EDGES 800000
#define C_H 128
#define C_OUT 64
#define NBLK 196          // ceil(50000/256)
#define TSTRIDE 136       // LDS tile row stride in bf16
#define E_PAD 1200128     // >= 800000 + 8*50000 (per-bucket x2 padding), 1024-aligned
#define MM_BLKS 782       // ceil(50000/64) row-tiles for the XW1 matmul
#define TILE_N 6250       // src-tile width: 6250 rows x 256 B = 1.6 MB (L2-resident)
#define GB 782            // gather blocks: 64 nodes/block, co-resident single generation

typedef __attribute__((ext_vector_type(8))) short bf16x8;
typedef __attribute__((ext_vector_type(4))) float f32x4;

static __device__ __forceinline__ float bf_lo(unsigned int u) { return __uint_as_float(u << 16); }
static __device__ __forceinline__ float bf_hi(unsigned int u) { return __uint_as_float(u & 0xffff0000u); }
static __device__ __forceinline__ unsigned short f2bf(float f) {
    __hip_bfloat16 h = __float2bfloat16(f);
    return *(unsigned short*)&h;
}
static __device__ __forceinline__ unsigned int pack2(float a, float b) {
    return (unsigned int)f2bf(a) | ((unsigned int)f2bf(b) << 16);
}
static __device__ __forceinline__ unsigned short f2h_bits(float f) {
    union { __half h; unsigned short u; } c; c.h = __float2half_rn(f); return c.u;
}
static __device__ __forceinline__ float h_bits2f(unsigned short u) {
    union { __half h; unsigned short u; } c; c.u = u; return __half2float(c.h);
}

// ================= prep: (dst,src-tile) hist(+rank) + pack W + zero epay ==========
// block ranges: [0,3125) hist | [3125,3413) pack | [3413,4585) zero
__global__ void prep_kernel(const int* __restrict__ src, const int* __restrict__ dst,
                            int* __restrict__ counts2,
                            int* __restrict__ rank,
                            const float* __restrict__ W1, const float* __restrict__ W2,
                            const float* __restrict__ W3, const float* __restrict__ Wd1,
                            const float* __restrict__ Wd2,
                            unsigned short* __restrict__ P1, unsigned short* __restrict__ P2,
                            unsigned short* __restrict__ P3, unsigned short* __restrict__ Pd1,
                            unsigned short* __restrict__ Pd2,
                            unsigned int* __restrict__ epay) {
    int b = blockIdx.x;
    if (b < 3125) {                               // hist over (dst, src-tile), capture rank
        int e = b * 256 + threadIdx.x;
        int d = dst[e], s = src[e];
        int t = s / TILE_N;                       // 0..7
        rank[e] = atomicAdd(&counts2[d * 8 + t], 1);
    } else if (b < 3413) {                        // pack weights
        int idx = (b - 3125) * 256 + threadIdx.x;
        if (idx < 4 * 16384) {
            int which = idx >> 14;
            int r = idx & 16383;
            const float* W = (which == 0) ? W1 : (which == 1) ? W2 : (which == 2) ? W3 : Wd1;
            unsigned short* P = (which == 0) ? P1 : (which == 1) ? P2 : (which == 2) ? P3 : Pd1;
            int j = r & 7, lane = (r >> 3) & 63, t = r >> 9;
            int nb = t & 7, kb = t >> 3;          // NB=8
            int k = kb * 32 + ((lane >> 4) << 3) + j;
            int n = nb * 16 + (lane & 15);
            P[r] = f2bf(W[(size_t)k * 128 + n]);
        } else {
            int r = idx - 65536;
            if (r < 8192) {
                int j = r & 7, lane = (r >> 3) & 63, t = r >> 9;
                int nb = t & 3, kb = t >> 2;      // NB=4
                int k = kb * 32 + ((lane >> 4) << 3) + j;
                int n = nb * 16 + (lane & 15);
                Pd2[r] = f2bf(Wd2[(size_t)k * 64 + n]);
            }
        }
    } else {                                      // zero epay: 1172 blocks x 1024 uints
        int i = (b - 3413) * 256 + threadIdx.x;
        *(uint4*)(epay + (size_t)i * 4) = make_uint4(0, 0, 0, 0);
    }
}

// ================= CSR scans (each (dst,tile) bucket padded to multiple of 2) =====
__global__ void __launch_bounds__(256) scan1_kernel(int* __restrict__ counts2,
                                                    int* __restrict__ eblk,
                                                    int* __restrict__ bsum,
                                                    float* __restrict__ dinv) {
    __shared__ int ws[4];
    int i = blockIdx.x * 256 + threadIdx.x;
    int vp = 0;
    if (i < N_NODES) {
        int* c = counts2 + (size_t)i * 8;
        uint4 a = *(uint4*)c;
        uint4 bq = *(uint4*)(c + 4);
        int raw = a.x + a.y + a.z + a.w + bq.x + bq.y + bq.z + bq.w;
        dinv[i] = rsqrtf((float)raw + 1.0f);
        int run = 0, tv;
        tv = ((int)a.x + 1) & ~1;  a.x  = run; run += tv;
        tv = ((int)a.y + 1) & ~1;  a.y  = run; run += tv;
        tv = ((int)a.z + 1) & ~1;  a.z  = run; run += tv;
        tv = ((int)a.w + 1) & ~1;  a.w  = run; run += tv;
        tv = ((int)bq.x + 1) & ~1; bq.x = run; run += tv;
        tv = ((int)bq.y + 1) & ~1; bq.y = run; run += tv;
        tv = ((int)bq.z + 1) & ~1; bq.z = run; run += tv;
        tv = ((int)bq.w + 1) & ~1; bq.w = run; run += tv;
        vp = run;
        *(uint4*)c = a;
        *(uint4*)(c + 4) = bq;
    }
    int lane = threadIdx.x & 63, w = threadIdx.x >> 6;
    int x = vp;
    #pragma unroll
    for (int off = 1; off < 64; off <<= 1) {
        int t = __shfl_up(x, off, 64);
        if (lane >= off) x += t;
    }
    if (lane == 63) ws[w] = x;
    __syncthreads();
    if (threadIdx.x == 0) {
        int run = 0;
        #pragma unroll
        for (int k = 0; k < 4; ++k) { int t = ws[k]; ws[k] = run; run += t; }
        bsum[blockIdx.x] = run;
    }
    __syncthreads();
    if (i < N_NODES) eblk[i] = x - vp + ws[w];
}

// merged scan2+scan3
__global__ void __launch_bounds__(256) scanB_kernel(const int* __restrict__ eblk,
                                                    const int* __restrict__ bsum,
                                                    int* __restrict__ rowptr) {
    __shared__ int ws[4];
    __shared__ int sbo;
    int i = threadIdx.x;
    int v = (i < NBLK) ? bsum[i] : 0;
    int lane = i & 63, w = i >> 6;
    int x = v;
    #pragma unroll
    for (int off = 1; off < 64; off <<= 1) {
        int t = __shfl_up(x, off, 64);
        if (lane >= off) x += t;
    }
    if (lane == 63) ws[w] = x;
    __syncthreads();
    if (i == 0) {
        int run = 0;
        #pragma unroll
        for (int k = 0; k < 4; ++k) { int t = ws[k]; ws[k] = run; run += t; }
    }
    __syncthreads();
    int excl = x - v + ws[w];
    if (i == (int)blockIdx.x) sbo = excl;
    if (blockIdx.x == 0 && i == NBLK - 1) rowptr[N_NODES] = excl + v;
    __syncthreads();
    int g = blockIdx.x * 256 + threadIdx.x;
    if (g < N_NODES) rowptr[g] = eblk[g] + sbo;
}

// ================= heterogeneous: XW1 matmul + csr fill (bucket-ordered) ==========
__global__ void __launch_bounds__(256) fill_mm_kernel(
        const float* __restrict__ x, const unsigned short* __restrict__ P1,
        unsigned short* __restrict__ XW1,
        const int* __restrict__ src, const int* __restrict__ dst,
        const float* __restrict__ dinv,
        const int* __restrict__ rowptr, const int* __restrict__ counts2,
        const int* __restrict__ rank,
        unsigned int* __restrict__ epay) {
    int b = blockIdx.x;
    if (b < MM_BLKS) {
        const int lane = threadIdx.x & 63;
        const int wave = threadIdx.x >> 6;
        const int wid  = b * 4 + wave;
        if (wid * 16 >= N_NODES) return;          // exact: 3125 waves used
        const int node = wid * 16 + (lane & 15);
        const int quad = lane >> 4;
        f32x4 acc[8];
        #pragma unroll
        for (int nb = 0; nb < 8; ++nb) acc[nb] = (f32x4){0.f, 0.f, 0.f, 0.f};
        #pragma unroll
        for (int kb = 0; kb < 4; ++kb) {
            const float* p = x + (size_t)node * 128 + kb * 32 + quad * 8;
            float4 lo = *(const float4*)p;
            float4 hi = *(const float4*)(p + 4);
            union { bf16x8 v; unsigned int u[4]; } tmp;
            tmp.u[0] = pack2(lo.x, lo.y); tmp.u[1] = pack2(lo.z, lo.w);
            tmp.u[2] = pack2(hi.x, hi.y); tmp.u[3] = pack2(hi.z, hi.w);
            #pragma unroll
            for (int nb = 0; nb < 8; ++nb) {
                bf16x8 wf = *(const bf16x8*)(P1 + ((size_t)(kb * 8 + nb) * 64 + lane) * 8);
                acc[nb] = __builtin_amdgcn_mfma_f32_16x16x32_bf16(wf, tmp.v, acc[nb], 0, 0, 0);
            }
        }
        #pragma unroll
        for (int nb = 0; nb < 8; ++nb) {
            int ch = nb * 16 + quad * 4;
            uint2 o;
            o.x = pack2(acc[nb][0], acc[nb][1]);
            o.y = pack2(acc[nb][2], acc[nb][3]);
            *(uint2*)(XW1 + (size_t)node * C_H + ch) = o;
        }
    } else {
        int e = (b - MM_BLKS) * 256 + threadIdx.x;
        if (e < N_EDGES) {
            int d = dst[e], s = src[e];
            int t = s / TILE_N;
            int pos = rowptr[d] + counts2[d * 8 + t] + rank[e];
            float nrm = dinv[s] * dinv[d];
            epay[pos] = (unsigned int)s | ((unsigned int)f2h_bits(nrm) << 16);
        }
    }
}

// ======== wave-per-node gather: 64 lanes x 2ch, 16 nodes/wave, tile-outer ========
// Wave-uniform edge walks (node uniform across the wave): zero divergence, every
// row read is one coalesced 256B transaction. Tile-outer/node-inner keeps all
// co-resident waves sweeping src-tiles in phase -> tile (1.6 MB) L2-resident.
static __device__ __forceinline__ void wave_gather16(
        const int* __restrict__ rowptr, const int* __restrict__ counts2,
        const unsigned int* __restrict__ epay,
        const float* __restrict__ dinv,
        const unsigned short* __restrict__ hin,
        int nbase, int lane2, float* accA, float* accB) {
    int rbase[16];
    #pragma unroll
    for (int nn = 0; nn < 16; ++nn) {
        int node = nbase + nn; if (node >= N_NODES) node = N_NODES - 1;
        float di = dinv[node], dii = di * di;
        unsigned int rw = *(const unsigned int*)(hin + (size_t)node * C_H + lane2);
        accA[nn] = bf_lo(rw) * dii;
        accB[nn] = bf_hi(rw) * dii;
        rbase[nn] = rowptr[node];
    }
    #pragma unroll 1
    for (int t = 0; t < 8; ++t) {
        #pragma unroll
        for (int nn = 0; nn < 16; ++nn) {
            int node = nbase + nn; if (node >= N_NODES) node = N_NODES - 1;
            const int* c2 = counts2 + (size_t)node * 8;
            int b0 = rbase[nn] + c2[t];
            int b1 = (t < 7) ? rbase[nn] + c2[t + 1] : rowptr[node + 1];
            float a = accA[nn], b = accB[nn];
            for (int p = b0; p < b1; p += 2) {
                uint2 ev = *(const uint2*)(epay + p);          // uniform -> broadcast
                unsigned int ra = *(const unsigned int*)(hin + (size_t)(ev.x & 0xffffu) * C_H + lane2);
                unsigned int rb = *(const unsigned int*)(hin + (size_t)(ev.y & 0xffffu) * C_H + lane2);
                float na = h_bits2f((unsigned short)(ev.x >> 16));
                float nb = h_bits2f((unsigned short)(ev.y >> 16));
                a = fmaf(bf_lo(ra), na, a); b = fmaf(bf_hi(ra), na, b);
                a = fmaf(bf_lo(rb), nb, a); b = fmaf(bf_hi(rb), nb, b);
            }
            accA[nn] = a; accB[nn] = b;
        }
    }
}

// ================= layer 1: pure gather(XW1) + bias + relu -> bf16 =================
__global__ void __launch_bounds__(256, 4) gather1_kernel(
        const int* __restrict__ rowptr, const int* __restrict__ counts2,
        const unsigned int* __restrict__ epay,
        const float* __restrict__ dinv,
        const unsigned short* __restrict__ hin,
        const float* __restrict__ bias,
        unsigned short* __restrict__ out) {
    const int t = threadIdx.x;
    const int lane = t & 63, wave = t >> 6;
    const int lane2 = lane * 2;
    const int nbase = blockIdx.x * 64 + wave * 16;

    float accA[16], accB[16];
    wave_gather16(rowptr, counts2, epay, dinv, hin, nbase, lane2, accA, accB);

    float b0 = bias[lane2], b1 = bias[lane2 + 1];
    #pragma unroll
    for (int nn = 0; nn < 16; ++nn) {
        int node = nbase + nn;
        if (node < N_NODES) {
            float v0 = fmaxf(accA[nn] + b0, 0.f);
            float v1 = fmaxf(accB[nn] + b1, 0.f);
            *(unsigned int*)(out + (size_t)node * C_H + lane2) = pack2(v0, v1);
        }
    }
}

// ========== fused layer: wave-per-node gather (64 nodes) -> LDS -> MFMA chain ======
template <bool FINAL>
__global__ void __launch_bounds__(256, 4) fused_layer_kernel(
        const int* __restrict__ rowptr, const int* __restrict__ counts2,
        const unsigned int* __restrict__ epay,
        const float* __restrict__ dinv,
        const unsigned short* __restrict__ hin,
        const unsigned short* __restrict__ Wp,
        const float* __restrict__ bias,
        const unsigned short* __restrict__ Wd1p,
        const float* __restrict__ bd1,
        const unsigned short* __restrict__ Wd2p,
        const float* __restrict__ bd2,
        unsigned short* __restrict__ out_b,
        float* __restrict__ out_f) {
    __shared__ unsigned short sA[64 * TSTRIDE];
    __shared__ unsigned short sB[64 * TSTRIDE];
    const int t = threadIdx.x;
    const int lane = t & 63, wave = t >> 6;

    // ---- phase A: gather 64 agg rows into sA (wave-uniform walks) ----
    {
        const int lane2 = lane * 2;
        const int nbase = blockIdx.x * 64 + wave * 16;
        float accA[16], accB[16];
        wave_gather16(rowptr, counts2, epay, dinv, hin, nbase, lane2, accA, accB);
        #pragma unroll
        for (int nn = 0; nn < 16; ++nn) {
            *(unsigned int*)(sA + (wave * 16 + nn) * TSTRIDE + lane2) =
                pack2(accA[nn], accB[nn]);
        }
    }
    __syncthreads();

    const int quad = lane >> 4, row = lane & 15;
    const int nb0 = 2 * wave, nb1 = 2 * wave + 1;

    // ---- mm1: relu(sA @ Wp + bias) ; 4 row-tiles per block ----
    #pragma unroll 1
    for (int rt = 0; rt < 4; ++rt) {
        const int lrow = rt * 16 + row;
        const int node = blockIdx.x * 64 + lrow;
        f32x4 acc0 = (f32x4){0.f, 0.f, 0.f, 0.f};
        f32x4 acc1 = (f32x4){0.f, 0.f, 0.f, 0.f};
        #pragma unroll
        for (int kb = 0; kb < 4; ++kb) {
            bf16x8 hf = *(const bf16x8*)(sA + lrow * TSTRIDE + kb * 32 + quad * 8);
            bf16x8 wf0 = *(const bf16x8*)(Wp + ((size_t)(kb * 8 + nb0) * 64 + lane) * 8);
            bf16x8 wf1 = *(const bf16x8*)(Wp + ((size_t)(kb * 8 + nb1) * 64 + lane) * 8);
            acc0 = __builtin_amdgcn_mfma_f32_16x16x32_bf16(wf0, hf, acc0, 0, 0, 0);
            acc1 = __builtin_amdgcn_mfma_f32_16x16x32_bf16(wf1, hf, acc1, 0, 0, 0);
        }
        float4 ba0 = *(const float4*)(bias + nb0 * 16 + quad * 4);
        float4 ba1 = *(const float4*)(bias + nb1 * 16 + quad * 4);
        float v00 = fmaxf(acc0[0] + ba0.x, 0.f), v01 = fmaxf(acc0[1] + ba0.y, 0.f);
        float v02 = fmaxf(acc0[2] + ba0.z, 0.f), v03 = fmaxf(acc0[3] + ba0.w, 0.f);
        float v10 = fmaxf(acc1[0] + ba1.x, 0.f), v11 = fmaxf(acc1[1] + ba1.y, 0.f);
        float v12 = fmaxf(acc1[2] + ba1.z, 0.f), v13 = fmaxf(acc1[3] + ba1.w, 0.f);
        uint2 o0, o1;
        o0.x = pack2(v00, v01); o0.y = pack2(v02, v03);
        o1.x = pack2(v10, v11); o1.y = pack2(v12, v13);
        if (!FINAL) {
            if (node < N_NODES) {
                *(uint2*)(out_b + (size_t)node * C_H + nb0 * 16 + quad * 4) = o0;
                *(uint2*)(out_b + (size_t)node * C_H + nb1 * 16 + quad * 4) = o1;
            }
        } else {
            *(uint2*)(sB + lrow * TSTRIDE + nb0 * 16 + quad * 4) = o0;
            *(uint2*)(sB + lrow * TSTRIDE + nb1 * 16 + quad * 4) = o1;
        }
    }
    if (!FINAL) return;

    __syncthreads();
    // ---- mm2: relu(sB @ Wd1 + bd1) -> sA ----
    #pragma unroll 1
    for (int rt = 0; rt < 4; ++rt) {
        const int lrow = rt * 16 + row;
        f32x4 acc0 = (f32x4){0.f, 0.f, 0.f, 0.f};
        f32x4 acc1 = (f32x4){0.f, 0.f, 0.f, 0.f};
        #pragma unroll
        for (int kb = 0; kb < 4; ++kb) {
            bf16x8 hf = *(const bf16x8*)(sB + lrow * TSTRIDE + kb * 32 + quad * 8);
            bf16x8 wf0 = *(const bf16x8*)(Wd1p + ((size_t)(kb * 8 + nb0) * 64 + lane) * 8);
            bf16x8 wf1 = *(const bf16x8*)(Wd1p + ((size_t)(kb * 8 + nb1) * 64 + lane) * 8);
            acc0 = __builtin_amdgcn_mfma_f32_16x16x32_bf16(wf0, hf, acc0, 0, 0, 0);
            acc1 = __builtin_amdgcn_mfma_f32_16x16x32_bf16(wf1, hf, acc1, 0, 0, 0);
        }
        float4 ba0 = *(const float4*)(bd1 + nb0 * 16 + quad * 4);
        float4 ba1 = *(const float4*)(bd1 + nb1 * 16 + quad * 4);
        float v00 = fmaxf(acc0[0] + ba0.x, 0.f), v01 = fmaxf(acc0[1] + ba0.y, 0.f);
        float v02 = fmaxf(acc0[2] + ba0.z, 0.f), v03 = fmaxf(acc0[3] + ba0.w, 0.f);
        float v10 = fmaxf(acc1[0] + ba1.x, 0.f), v11 = fmaxf(acc1[1] + ba1.y, 0.f);
        float v12 = fmaxf(acc1[2] + ba1.z, 0.f), v13 = fmaxf(acc1[3] + ba1.w, 0.f);
        uint2 o0, o1;
        o0.x = pack2(v00, v01); o0.y = pack2(v02, v03);
        o1.x = pack2(v10, v11); o1.y = pack2(v12, v13);
        *(uint2*)(sA + lrow * TSTRIDE + nb0 * 16 + quad * 4) = o0;
        *(uint2*)(sA + lrow * TSTRIDE + nb1 * 16 + quad * 4) = o1;
    }
    __syncthreads();

    // ---- mm3: sA @ Wd2 + bd2 -> sigmoid -> out_f ----
    #pragma unroll 1
    for (int rt = 0; rt < 4; ++rt) {
        const int lrow = rt * 16 + row;
        const int node = blockIdx.x * 64 + lrow;
        f32x4 acc = (f32x4){0.f, 0.f, 0.f, 0.f};
        #pragma unroll
        for (int kb = 0; kb < 4; ++kb) {
            bf16x8 hf = *(const bf16x8*)(sA + lrow * TSTRIDE + kb * 32 + quad * 8);
            bf16x8 wf = *(const bf16x8*)(Wd2p + ((size_t)(kb * 4 + wave) * 64 + lane) * 8);
            acc = __builtin_amdgcn_mfma_f32_16x16x32_bf16(wf, hf, acc, 0, 0, 0);
        }
        if (node < N_NODES) {
            int ch = wave * 16 + quad * 4;
            float4 b4 = *(const float4*)(bd2 + ch);
            float4 rr;
            rr.x = 1.f / (1.f + expf(-(acc[0] + b4.x)));
            rr.y = 1.f / (1.f + expf(-(acc[1] + b4.y)));
            rr.z = 1.f / (1.f + expf(-(acc[2] + b4.z)));
            rr.w = 1.f / (1.f + expf(-(acc[3] + b4.w)));
            *(float4*)(out_f + (size_t)node * C_OUT + ch) = rr;
        }
    }
}

extern "C" void kernel_launch(void* const* d_in, const int* in_sizes, int n_in,
                              void* d_out, int out_size, void* d_ws, size_t ws_size,
                              hipStream_t stream) {
    const float* x   = (const float*)d_in[0];
    const int*   ei  = (const int*)d_in[1];
    const float* W1  = (const float*)d_in[2];
    const float* b1  = (const float*)d_in[3];
    const float* W2  = (const float*)d_in[4];
    const float* b2  = (const float*)d_in[5];
    const float* W3  = (const float*)d_in[6];
    const float* b3  = (const float*)d_in[7];
    const float* Wd1 = (const float*)d_in[8];
    const float* bd1 = (const float*)d_in[9];
    const float* Wd2 = (const float*)d_in[10];
    const float* bd2 = (const float*)d_in[11];

    const int* src = ei;
    const int* dst = ei + N_EDGES;

    char* base = (char*)d_ws;
    size_t off = 0;
    auto alloc = [&](size_t bytes) { char* p = base + off; off += (bytes + 255) & ~size_t(255); return p; };
    int*            counts2 = (int*)alloc((size_t)N_NODES * 8 * 4);
    unsigned int*   epay   = (unsigned int*)alloc((size_t)E_PAD * 4);
    int*            rank   = (int*)alloc((size_t)N_EDGES * 4);
    float*          dinv   = (float*)alloc(N_NODES * 4);
    int*            rowptr = (int*)alloc((N_NODES + 1) * 4);
    int*            eblk   = (int*)alloc(N_NODES * 4);
    int*            bsum   = (int*)alloc(256 * 4);
    unsigned short* XW1    = (unsigned short*)alloc((size_t)N_NODES * C_H * 2);
    unsigned short* bufA   = (unsigned short*)alloc((size_t)N_NODES * C_H * 2);
    unsigned short* bufB   = (unsigned short*)alloc((size_t)N_NODES * C_H * 2);
    unsigned short* P1     = (unsigned short*)alloc(128 * 128 * 2);
    unsigned short* P2     = (unsigned short*)alloc(128 * 128 * 2);
    unsigned short* P3     = (unsigned short*)alloc(128 * 128 * 2);
    unsigned short* Pd1    = (unsigned short*)alloc(128 * 128 * 2);
    unsigned short* Pd2    = (unsigned short*)alloc(128 * 64 * 2);

    const int T = 256;
    dim3 blk(T);
    dim3 gN((N_NODES + T - 1) / T);            // 196
    dim3 gPrep(3125 + 288 + 1172);             // hist + pack + zero (E_PAD/1024)
    dim3 gFillMM(MM_BLKS + 3125);              // mm + fill
    dim3 gGB(GB);                              // 782 co-resident gather blocks

    hipMemsetAsync(counts2, 0, (size_t)N_NODES * 8 * 4, stream);
    prep_kernel<<<gPrep, blk, 0, stream>>>(src, dst, counts2, rank,
                                           W1, W2, W3, Wd1, Wd2,
                                           P1, P2, P3, Pd1, Pd2, epay);
    scan1_kernel<<<gN, blk, 0, stream>>>(counts2, eblk, bsum, dinv);
    scanB_kernel<<<gN, blk, 0, stream>>>(eblk, bsum, rowptr);
    fill_mm_kernel<<<gFillMM, blk, 0, stream>>>(x, P1, XW1, src, dst, dinv,
                                                rowptr, counts2, rank, epay);

    // ---- layer 1: relu(agg(XW1) + b1) -> bufA ----
    gather1_kernel<<<gGB, blk, 0, stream>>>(rowptr, counts2, epay, dinv, XW1, b1, bufA);
    // ---- layer 2 ----
    fused_layer_kernel<false><<<gGB, blk, 0, stream>>>(
        rowptr, counts2, epay, dinv, bufA, P2, b2, nullptr, nullptr, nullptr, nullptr, bufB, nullptr);
    // ---- layer 3 + dense head ----
    fused_layer_kernel<true><<<gGB, blk, 0, stream>>>(
        rowptr, counts2, epay, dinv, bufB, P3, b3, Pd1, bd1, Pd2, bd2, nullptr, (float*)d_out);
}

// Round 10
// 262.583 us; speedup vs baseline: 2.1894x; 2.1894x over previous
//
#include <hip/hip_runtime.h>
#include <hip/hip_bf16.h>
#include <hip/hip_fp16.h>

#define N_NODES 50000
#define N_EDGES 800000
#define C_H 128
#define C_OUT 64
#define NBLK 196          // ceil(50000/256)
#define TSTRIDE 136       // LDS tile row stride in bf16
#define E_PAD 1200128     // >= 800000 + 8*50000 (per-bucket x2 padding), 1024-aligned
#define MM_BLKS 782       // ceil(50000/64) row-tiles for the XW1 matmul
#define TILE_N 6250       // src-tile width: 6250 rows x 256 B = 1.6 MB (L2-resident)
#define GG 1563           // gather grid: 32 nodes/block, 8 thr/node

typedef __attribute__((ext_vector_type(8))) short bf16x8;
typedef __attribute__((ext_vector_type(4))) float f32x4;

static __device__ __forceinline__ float bf_lo(unsigned int u) { return __uint_as_float(u << 16); }
static __device__ __forceinline__ float bf_hi(unsigned int u) { return __uint_as_float(u & 0xffff0000u); }
static __device__ __forceinline__ unsigned short f2bf(float f) {
    __hip_bfloat16 h = __float2bfloat16(f);
    return *(unsigned short*)&h;
}
static __device__ __forceinline__ unsigned int pack2(float a, float b) {
    return (unsigned int)f2bf(a) | ((unsigned int)f2bf(b) << 16);
}
static __device__ __forceinline__ unsigned short f2h_bits(float f) {
    union { __half h; unsigned short u; } c; c.h = __float2half_rn(f); return c.u;
}
static __device__ __forceinline__ float h_bits2f(unsigned short u) {
    union { __half h; unsigned short u; } c; c.u = u; return __half2float(c.h);
}

// ================= prep: (dst,src-tile) hist(+rank) + pack W + zero epay ==========
// block ranges: [0,3125) hist | [3125,3413) pack | [3413,4585) zero
__global__ void prep_kernel(const int* __restrict__ src, const int* __restrict__ dst,
                            int* __restrict__ counts2,
                            int* __restrict__ rank,
                            const float* __restrict__ W1, const float* __restrict__ W2,
                            const float* __restrict__ W3, const float* __restrict__ Wd1,
                            const float* __restrict__ Wd2,
                            unsigned short* __restrict__ P1, unsigned short* __restrict__ P2,
                            unsigned short* __restrict__ P3, unsigned short* __restrict__ Pd1,
                            unsigned short* __restrict__ Pd2,
                            unsigned int* __restrict__ epay) {
    int b = blockIdx.x;
    if (b < 3125) {                               // hist over (dst, src-tile), capture rank
        int e = b * 256 + threadIdx.x;
        int d = dst[e], s = src[e];
        int t = s / TILE_N;                       // 0..7
        rank[e] = atomicAdd(&counts2[d * 8 + t], 1);
    } else if (b < 3413) {                        // pack weights
        int idx = (b - 3125) * 256 + threadIdx.x;
        if (idx < 4 * 16384) {
            int which = idx >> 14;
            int r = idx & 16383;
            const float* W = (which == 0) ? W1 : (which == 1) ? W2 : (which == 2) ? W3 : Wd1;
            unsigned short* P = (which == 0) ? P1 : (which == 1) ? P2 : (which == 2) ? P3 : Pd1;
            int j = r & 7, lane = (r >> 3) & 63, t = r >> 9;
            int nb = t & 7, kb = t >> 3;          // NB=8
            int k = kb * 32 + ((lane >> 4) << 3) + j;
            int n = nb * 16 + (lane & 15);
            P[r] = f2bf(W[(size_t)k * 128 + n]);
        } else {
            int r = idx - 65536;
            if (r < 8192) {
                int j = r & 7, lane = (r >> 3) & 63, t = r >> 9;
                int nb = t & 3, kb = t >> 2;      // NB=4
                int k = kb * 32 + ((lane >> 4) << 3) + j;
                int n = nb * 16 + (lane & 15);
                Pd2[r] = f2bf(Wd2[(size_t)k * 64 + n]);
            }
        }
    } else {                                      // zero epay: 1172 blocks x 1024 uints
        int i = (b - 3413) * 256 + threadIdx.x;
        *(uint4*)(epay + (size_t)i * 4) = make_uint4(0, 0, 0, 0);
    }
}

// ================= CSR scans (each (dst,tile) bucket padded to multiple of 2) =====
__global__ void __launch_bounds__(256) scan1_kernel(int* __restrict__ counts2,
                                                    int* __restrict__ eblk,
                                                    int* __restrict__ bsum,
                                                    float* __restrict__ dinv) {
    __shared__ int ws[4];
    int i = blockIdx.x * 256 + threadIdx.x;
    int vp = 0;
    if (i < N_NODES) {
        int* c = counts2 + (size_t)i * 8;
        uint4 a = *(uint4*)c;
        uint4 bq = *(uint4*)(c + 4);
        int raw = a.x + a.y + a.z + a.w + bq.x + bq.y + bq.z + bq.w;
        dinv[i] = rsqrtf((float)raw + 1.0f);
        int run = 0, tv;
        tv = ((int)a.x + 1) & ~1;  a.x  = run; run += tv;
        tv = ((int)a.y + 1) & ~1;  a.y  = run; run += tv;
        tv = ((int)a.z + 1) & ~1;  a.z  = run; run += tv;
        tv = ((int)a.w + 1) & ~1;  a.w  = run; run += tv;
        tv = ((int)bq.x + 1) & ~1; bq.x = run; run += tv;
        tv = ((int)bq.y + 1) & ~1; bq.y = run; run += tv;
        tv = ((int)bq.z + 1) & ~1; bq.z = run; run += tv;
        tv = ((int)bq.w + 1) & ~1; bq.w = run; run += tv;
        vp = run;
        *(uint4*)c = a;
        *(uint4*)(c + 4) = bq;
    }
    int lane = threadIdx.x & 63, w = threadIdx.x >> 6;
    int x = vp;
    #pragma unroll
    for (int off = 1; off < 64; off <<= 1) {
        int t = __shfl_up(x, off, 64);
        if (lane >= off) x += t;
    }
    if (lane == 63) ws[w] = x;
    __syncthreads();
    if (threadIdx.x == 0) {
        int run = 0;
        #pragma unroll
        for (int k = 0; k < 4; ++k) { int t = ws[k]; ws[k] = run; run += t; }
        bsum[blockIdx.x] = run;
    }
    __syncthreads();
    if (i < N_NODES) eblk[i] = x - vp + ws[w];
}

// merged scan2+scan3
__global__ void __launch_bounds__(256) scanB_kernel(const int* __restrict__ eblk,
                                                    const int* __restrict__ bsum,
                                                    int* __restrict__ rowptr) {
    __shared__ int ws[4];
    __shared__ int sbo;
    int i = threadIdx.x;
    int v = (i < NBLK) ? bsum[i] : 0;
    int lane = i & 63, w = i >> 6;
    int x = v;
    #pragma unroll
    for (int off = 1; off < 64; off <<= 1) {
        int t = __shfl_up(x, off, 64);
        if (lane >= off) x += t;
    }
    if (lane == 63) ws[w] = x;
    __syncthreads();
    if (i == 0) {
        int run = 0;
        #pragma unroll
        for (int k = 0; k < 4; ++k) { int t = ws[k]; ws[k] = run; run += t; }
    }
    __syncthreads();
    int excl = x - v + ws[w];
    if (i == (int)blockIdx.x) sbo = excl;
    if (blockIdx.x == 0 && i == NBLK - 1) rowptr[N_NODES] = excl + v;
    __syncthreads();
    int g = blockIdx.x * 256 + threadIdx.x;
    if (g < N_NODES) rowptr[g] = eblk[g] + sbo;
}

// ================= heterogeneous: XW1 matmul + csr fill (bucket-ordered) ==========
__global__ void __launch_bounds__(256) fill_mm_kernel(
        const float* __restrict__ x, const unsigned short* __restrict__ P1,
        unsigned short* __restrict__ XW1,
        const int* __restrict__ src, const int* __restrict__ dst,
        const float* __restrict__ dinv,
        const int* __restrict__ rowptr, const int* __restrict__ counts2,
        const int* __restrict__ rank,
        unsigned int* __restrict__ epay) {
    int b = blockIdx.x;
    if (b < MM_BLKS) {
        const int lane = threadIdx.x & 63;
        const int wave = threadIdx.x >> 6;
        const int wid  = b * 4 + wave;
        if (wid * 16 >= N_NODES) return;          // exact: 3125 waves used
        const int node = wid * 16 + (lane & 15);
        const int quad = lane >> 4;
        f32x4 acc[8];
        #pragma unroll
        for (int nb = 0; nb < 8; ++nb) acc[nb] = (f32x4){0.f, 0.f, 0.f, 0.f};
        #pragma unroll
        for (int kb = 0; kb < 4; ++kb) {
            const float* p = x + (size_t)node * 128 + kb * 32 + quad * 8;
            float4 lo = *(const float4*)p;
            float4 hi = *(const float4*)(p + 4);
            union { bf16x8 v; unsigned int u[4]; } tmp;
            tmp.u[0] = pack2(lo.x, lo.y); tmp.u[1] = pack2(lo.z, lo.w);
            tmp.u[2] = pack2(hi.x, hi.y); tmp.u[3] = pack2(hi.z, hi.w);
            #pragma unroll
            for (int nb = 0; nb < 8; ++nb) {
                bf16x8 wf = *(const bf16x8*)(P1 + ((size_t)(kb * 8 + nb) * 64 + lane) * 8);
                acc[nb] = __builtin_amdgcn_mfma_f32_16x16x32_bf16(wf, tmp.v, acc[nb], 0, 0, 0);
            }
        }
        #pragma unroll
        for (int nb = 0; nb < 8; ++nb) {
            int ch = nb * 16 + quad * 4;
            uint2 o;
            o.x = pack2(acc[nb][0], acc[nb][1]);
            o.y = pack2(acc[nb][2], acc[nb][3]);
            *(uint2*)(XW1 + (size_t)node * C_H + ch) = o;
        }
    } else {
        int e = (b - MM_BLKS) * 256 + threadIdx.x;
        if (e < N_EDGES) {
            int d = dst[e], s = src[e];
            int t = s / TILE_N;
            int pos = rowptr[d] + counts2[d * 8 + t] + rank[e];
            float nrm = dinv[s] * dinv[d];
            epay[pos] = (unsigned int)s | ((unsigned int)f2h_bits(nrm) << 16);
        }
    }
}

// ========= thread-per-node 16ch walker: preloaded bounds, tile-bucket order =======
static __device__ __forceinline__ void fma8v(float* a, uint4 q, float nm) {
    a[0] = fmaf(bf_lo(q.x), nm, a[0]); a[1] = fmaf(bf_hi(q.x), nm, a[1]);
    a[2] = fmaf(bf_lo(q.y), nm, a[2]); a[3] = fmaf(bf_hi(q.y), nm, a[3]);
    a[4] = fmaf(bf_lo(q.z), nm, a[4]); a[5] = fmaf(bf_hi(q.z), nm, a[5]);
    a[6] = fmaf(bf_lo(q.w), nm, a[6]); a[7] = fmaf(bf_hi(q.w), nm, a[7]);
}

static __device__ __forceinline__ void agg16(
        const int* __restrict__ rowptr, const int* __restrict__ counts2,
        const unsigned int* __restrict__ epay,
        const float* __restrict__ dinv,
        const unsigned short* __restrict__ hin,
        int node, int c16, float* acc) {
    const unsigned short* hc = hin + c16;
    float di = dinv[node], dii = di * di;
    {
        const unsigned short* rp = hc + (size_t)node * C_H;
        uint4 q0 = *(const uint4*)rp, q1 = *(const uint4*)(rp + 8);
        fma8v(acc, q0, dii); fma8v(acc + 8, q1, dii);
    }
    int base = rowptr[node];
    int rend = rowptr[node + 1];
    const int* c2 = counts2 + (size_t)node * 8;
    uint4 o0 = *(const uint4*)c2;
    uint4 o1 = *(const uint4*)(c2 + 4);
    int off[9];
    off[0] = o0.x; off[1] = o0.y; off[2] = o0.z; off[3] = o0.w;
    off[4] = o1.x; off[5] = o1.y; off[6] = o1.z; off[7] = o1.w;
    off[8] = rend - base;
    #pragma unroll
    for (int t = 0; t < 8; ++t) {
        int b0 = base + off[t];
        int b1 = base + off[t + 1];
        for (int p = b0; p < b1; p += 2) {
            uint2 ev = *(const uint2*)(epay + p);
            const unsigned short* ra = hc + (size_t)(ev.x & 0xffffu) * C_H;
            const unsigned short* rb = hc + (size_t)(ev.y & 0xffffu) * C_H;
            uint4 a0 = *(const uint4*)ra,  a1 = *(const uint4*)(ra + 8);
            uint4 c0 = *(const uint4*)rb,  c1 = *(const uint4*)(rb + 8);
            float na = h_bits2f((unsigned short)(ev.x >> 16));
            float nb = h_bits2f((unsigned short)(ev.y >> 16));
            fma8v(acc, a0, na); fma8v(acc + 8, a1, na);
            fma8v(acc, c0, nb); fma8v(acc + 8, c1, nb);
        }
    }
}

// ================= layer 1: pure gather(XW1) + bias + relu -> bf16 =================
// 32 nodes/block x 8 thr/node x 16 ch; grid 1563 (~6 blocks/CU, ~24 waves/CU).
__global__ void __launch_bounds__(256, 4) gather1_kernel(
        const int* __restrict__ rowptr, const int* __restrict__ counts2,
        const unsigned int* __restrict__ epay,
        const float* __restrict__ dinv,
        const unsigned short* __restrict__ hin,
        const float* __restrict__ bias,
        unsigned short* __restrict__ out) {
    const int t = threadIdx.x;
    const int node = blockIdx.x * 32 + (t >> 3);
    if (node >= N_NODES) return;
    const int c16 = (t & 7) << 4;

    float acc[16];
    #pragma unroll
    for (int j = 0; j < 16; ++j) acc[j] = 0.f;
    agg16(rowptr, counts2, epay, dinv, hin, node, c16, acc);

    #pragma unroll
    for (int g = 0; g < 2; ++g) {
        float4 ba = *(const float4*)(bias + c16 + g * 8);
        float4 bb = *(const float4*)(bias + c16 + g * 8 + 4);
        float v0 = fmaxf(acc[g*8+0] + ba.x, 0.f), v1 = fmaxf(acc[g*8+1] + ba.y, 0.f);
        float v2 = fmaxf(acc[g*8+2] + ba.z, 0.f), v3 = fmaxf(acc[g*8+3] + ba.w, 0.f);
        float v4 = fmaxf(acc[g*8+4] + bb.x, 0.f), v5 = fmaxf(acc[g*8+5] + bb.y, 0.f);
        float v6 = fmaxf(acc[g*8+6] + bb.z, 0.f), v7 = fmaxf(acc[g*8+7] + bb.w, 0.f);
        uint4 o;
        o.x = pack2(v0, v1); o.y = pack2(v2, v3);
        o.z = pack2(v4, v5); o.w = pack2(v6, v7);
        *(uint4*)(out + (size_t)node * C_H + c16 + g * 8) = o;
    }
}

// ========== fused layer: 32-node gather -> LDS -> MFMA chain (cond. sB) ============
template <bool FINAL>
__global__ void __launch_bounds__(256, 4) fused_layer_kernel(
        const int* __restrict__ rowptr, const int* __restrict__ counts2,
        const unsigned int* __restrict__ epay,
        const float* __restrict__ dinv,
        const unsigned short* __restrict__ hin,
        const unsigned short* __restrict__ Wp,
        const float* __restrict__ bias,
        const unsigned short* __restrict__ Wd1p,
        const float* __restrict__ bd1,
        const unsigned short* __restrict__ Wd2p,
        const float* __restrict__ bd2,
        unsigned short* __restrict__ out_b,
        float* __restrict__ out_f) {
    __shared__ unsigned short sA[32 * TSTRIDE];
    __shared__ unsigned short sB[FINAL ? 32 * TSTRIDE : 8];
    const int t = threadIdx.x;

    // ---- phase A: gather 32 agg rows into sA ----
    {
        const int ln = t >> 3;
        const int node = blockIdx.x * 32 + ln;
        const int c16 = (t & 7) << 4;
        float acc[16];
        #pragma unroll
        for (int j = 0; j < 16; ++j) acc[j] = 0.f;
        if (node < N_NODES)
            agg16(rowptr, counts2, epay, dinv, hin, node, c16, acc);
        #pragma unroll
        for (int g = 0; g < 2; ++g) {
            uint4 o;
            o.x = pack2(acc[g*8+0], acc[g*8+1]); o.y = pack2(acc[g*8+2], acc[g*8+3]);
            o.z = pack2(acc[g*8+4], acc[g*8+5]); o.w = pack2(acc[g*8+6], acc[g*8+7]);
            *(uint4*)(sA + ln * TSTRIDE + c16 + g * 8) = o;
        }
    }
    __syncthreads();

    const int lane = t & 63, wave = t >> 6, quad = lane >> 4, row = lane & 15;
    const int nb0 = 2 * wave, nb1 = 2 * wave + 1;

    // ---- mm1: relu(sA @ Wp + bias) ; 2 row-tiles per block ----
    #pragma unroll 1
    for (int rt = 0; rt < 2; ++rt) {
        const int lrow = rt * 16 + row;
        const int node = blockIdx.x * 32 + lrow;
        f32x4 acc0 = (f32x4){0.f, 0.f, 0.f, 0.f};
        f32x4 acc1 = (f32x4){0.f, 0.f, 0.f, 0.f};
        #pragma unroll
        for (int kb = 0; kb < 4; ++kb) {
            bf16x8 hf = *(const bf16x8*)(sA + lrow * TSTRIDE + kb * 32 + quad * 8);
            bf16x8 wf0 = *(const bf16x8*)(Wp + ((size_t)(kb * 8 + nb0) * 64 + lane) * 8);
            bf16x8 wf1 = *(const bf16x8*)(Wp + ((size_t)(kb * 8 + nb1) * 64 + lane) * 8);
            acc0 = __builtin_amdgcn_mfma_f32_16x16x32_bf16(wf0, hf, acc0, 0, 0, 0);
            acc1 = __builtin_amdgcn_mfma_f32_16x16x32_bf16(wf1, hf, acc1, 0, 0, 0);
        }
        float4 ba0 = *(const float4*)(bias + nb0 * 16 + quad * 4);
        float4 ba1 = *(const float4*)(bias + nb1 * 16 + quad * 4);
        float v00 = fmaxf(acc0[0] + ba0.x, 0.f), v01 = fmaxf(acc0[1] + ba0.y, 0.f);
        float v02 = fmaxf(acc0[2] + ba0.z, 0.f), v03 = fmaxf(acc0[3] + ba0.w, 0.f);
        float v10 = fmaxf(acc1[0] + ba1.x, 0.f), v11 = fmaxf(acc1[1] + ba1.y, 0.f);
        float v12 = fmaxf(acc1[2] + ba1.z, 0.f), v13 = fmaxf(acc1[3] + ba1.w, 0.f);
        uint2 o0, o1;
        o0.x = pack2(v00, v01); o0.y = pack2(v02, v03);
        o1.x = pack2(v10, v11); o1.y = pack2(v12, v13);
        if (!FINAL) {
            if (node < N_NODES) {
                *(uint2*)(out_b + (size_t)node * C_H + nb0 * 16 + quad * 4) = o0;
                *(uint2*)(out_b + (size_t)node * C_H + nb1 * 16 + quad * 4) = o1;
            }
        } else {
            *(uint2*)(sB + lrow * TSTRIDE + nb0 * 16 + quad * 4) = o0;
            *(uint2*)(sB + lrow * TSTRIDE + nb1 * 16 + quad * 4) = o1;
        }
    }
    if (!FINAL) return;

    __syncthreads();
    // ---- mm2: relu(sB @ Wd1 + bd1) -> sA ----
    #pragma unroll 1
    for (int rt = 0; rt < 2; ++rt) {
        const int lrow = rt * 16 + row;
        f32x4 acc0 = (f32x4){0.f, 0.f, 0.f, 0.f};
        f32x4 acc1 = (f32x4){0.f, 0.f, 0.f, 0.f};
        #pragma unroll
        for (int kb = 0; kb < 4; ++kb) {
            bf16x8 hf = *(const bf16x8*)(sB + lrow * TSTRIDE + kb * 32 + quad * 8);
            bf16x8 wf0 = *(const bf16x8*)(Wd1p + ((size_t)(kb * 8 + nb0) * 64 + lane) * 8);
            bf16x8 wf1 = *(const bf16x8*)(Wd1p + ((size_t)(kb * 8 + nb1) * 64 + lane) * 8);
            acc0 = __builtin_amdgcn_mfma_f32_16x16x32_bf16(wf0, hf, acc0, 0, 0, 0);
            acc1 = __builtin_amdgcn_mfma_f32_16x16x32_bf16(wf1, hf, acc1, 0, 0, 0);
        }
        float4 ba0 = *(const float4*)(bd1 + nb0 * 16 + quad * 4);
        float4 ba1 = *(const float4*)(bd1 + nb1 * 16 + quad * 4);
        float v00 = fmaxf(acc0[0] + ba0.x, 0.f), v01 = fmaxf(acc0[1] + ba0.y, 0.f);
        float v02 = fmaxf(acc0[2] + ba0.z, 0.f), v03 = fmaxf(acc0[3] + ba0.w, 0.f);
        float v10 = fmaxf(acc1[0] + ba1.x, 0.f), v11 = fmaxf(acc1[1] + ba1.y, 0.f);
        float v12 = fmaxf(acc1[2] + ba1.z, 0.f), v13 = fmaxf(acc1[3] + ba1.w, 0.f);
        uint2 o0, o1;
        o0.x = pack2(v00, v01); o0.y = pack2(v02, v03);
        o1.x = pack2(v10, v11); o1.y = pack2(v12, v13);
        *(uint2*)(sA + lrow * TSTRIDE + nb0 * 16 + quad * 4) = o0;
        *(uint2*)(sA + lrow * TSTRIDE + nb1 * 16 + quad * 4) = o1;
    }
    __syncthreads();

    // ---- mm3: sA @ Wd2 + bd2 -> sigmoid -> out_f ----
    #pragma unroll 1
    for (int rt = 0; rt < 2; ++rt) {
        const int lrow = rt * 16 + row;
        const int node = blockIdx.x * 32 + lrow;
        f32x4 acc = (f32x4){0.f, 0.f, 0.f, 0.f};
        #pragma unroll
        for (int kb = 0; kb < 4; ++kb) {
            bf16x8 hf = *(const bf16x8*)(sA + lrow * TSTRIDE + kb * 32 + quad * 8);
            bf16x8 wf = *(const bf16x8*)(Wd2p + ((size_t)(kb * 4 + wave) * 64 + lane) * 8);
            acc = __builtin_amdgcn_mfma_f32_16x16x32_bf16(wf, hf, acc, 0, 0, 0);
        }
        if (node < N_NODES) {
            int ch = wave * 16 + quad * 4;
            float4 b4 = *(const float4*)(bd2 + ch);
            float4 rr;
            rr.x = 1.f / (1.f + expf(-(acc[0] + b4.x)));
            rr.y = 1.f / (1.f + expf(-(acc[1] + b4.y)));
            rr.z = 1.f / (1.f + expf(-(acc[2] + b4.z)));
            rr.w = 1.f / (1.f + expf(-(acc[3] + b4.w)));
            *(float4*)(out_f + (size_t)node * C_OUT + ch) = rr;
        }
    }
}

extern "C" void kernel_launch(void* const* d_in, const int* in_sizes, int n_in,
                              void* d_out, int out_size, void* d_ws, size_t ws_size,
                              hipStream_t stream) {
    const float* x   = (const float*)d_in[0];
    const int*   ei  = (const int*)d_in[1];
    const float* W1  = (const float*)d_in[2];
    const float* b1  = (const float*)d_in[3];
    const float* W2  = (const float*)d_in[4];
    const float* b2  = (const float*)d_in[5];
    const float* W3  = (const float*)d_in[6];
    const float* b3  = (const float*)d_in[7];
    const float* Wd1 = (const float*)d_in[8];
    const float* bd1 = (const float*)d_in[9];
    const float* Wd2 = (const float*)d_in[10];
    const float* bd2 = (const float*)d_in[11];

    const int* src = ei;
    const int* dst = ei + N_EDGES;

    char* base = (char*)d_ws;
    size_t off = 0;
    auto alloc = [&](size_t bytes) { char* p = base + off; off += (bytes + 255) & ~size_t(255); return p; };
    int*            counts2 = (int*)alloc((size_t)N_NODES * 8 * 4);
    unsigned int*   epay   = (unsigned int*)alloc((size_t)E_PAD * 4);
    int*            rank   = (int*)alloc((size_t)N_EDGES * 4);
    float*          dinv   = (float*)alloc(N_NODES * 4);
    int*            rowptr = (int*)alloc((N_NODES + 1) * 4);
    int*            eblk   = (int*)alloc(N_NODES * 4);
    int*            bsum   = (int*)alloc(256 * 4);
    unsigned short* XW1    = (unsigned short*)alloc((size_t)N_NODES * C_H * 2);
    unsigned short* bufA   = (unsigned short*)alloc((size_t)N_NODES * C_H * 2);
    unsigned short* bufB   = (unsigned short*)alloc((size_t)N_NODES * C_H * 2);
    unsigned short* P1     = (unsigned short*)alloc(128 * 128 * 2);
    unsigned short* P2     = (unsigned short*)alloc(128 * 128 * 2);
    unsigned short* P3     = (unsigned short*)alloc(128 * 128 * 2);
    unsigned short* Pd1    = (unsigned short*)alloc(128 * 128 * 2);
    unsigned short* Pd2    = (unsigned short*)alloc(128 * 64 * 2);

    const int T = 256;
    dim3 blk(T);
    dim3 gN((N_NODES + T - 1) / T);            // 196
    dim3 gPrep(3125 + 288 + 1172);             // hist + pack + zero (E_PAD/1024)
    dim3 gFillMM(MM_BLKS + 3125);              // mm + fill
    dim3 gG(GG);                               // 1563 gather blocks (32 nodes each)

    hipMemsetAsync(counts2, 0, (size_t)N_NODES * 8 * 4, stream);
    prep_kernel<<<gPrep, blk, 0, stream>>>(src, dst, counts2, rank,
                                           W1, W2, W3, Wd1, Wd2,
                                           P1, P2, P3, Pd1, Pd2, epay);
    scan1_kernel<<<gN, blk, 0, stream>>>(counts2, eblk, bsum, dinv);
    scanB_kernel<<<gN, blk, 0, stream>>>(eblk, bsum, rowptr);
    fill_mm_kernel<<<gFillMM, blk, 0, stream>>>(x, P1, XW1, src, dst, dinv,
                                                rowptr, counts2, rank, epay);

    // ---- layer 1: relu(agg(XW1) + b1) -> bufA ----
    gather1_kernel<<<gG, blk, 0, stream>>>(rowptr, counts2, epay, dinv, XW1, b1, bufA);
    // ---- layer 2 ----
    fused_layer_kernel<false><<<gG, blk, 0, stream>>>(
        rowptr, counts2, epay, dinv, bufA, P2, b2, nullptr, nullptr, nullptr, nullptr, bufB, nullptr);
    // ---- layer 3 + dense head ----
    fused_layer_kernel<true><<<gG, blk, 0, stream>>>(
        rowptr, counts2, epay, dinv, bufB, P3, b3, Pd1, bd1, Pd2, bd2, nullptr, (float*)d_out);
}

// Round 11
// 254.285 us; speedup vs baseline: 2.2608x; 1.0326x over previous
//
#include <hip/hip_runtime.h>
#include <hip/hip_bf16.h>
#include <hip/hip_fp16.h>

#define N_NODES 50000
#define N_EDGES 800000
#define C_H 128
#define C_OUT 64
#define NBLK 196          // ceil(50000/256)
#define TSTRIDE 136       // LDS tile row stride in bf16
#define E_PAD 950272      // >= N_EDGES + 3*N_NODES, 1024-aligned
#define MM_BLKS 782       // ceil(50000/64) row-tiles for the XW1 matmul
#define TILE_N 6250       // src-tile width (8 tiles): 6250 rows x 256 B = 1.6 MB, L2-line-resident

typedef __attribute__((ext_vector_type(8))) short bf16x8;
typedef __attribute__((ext_vector_type(4))) float f32x4;

static __device__ __forceinline__ float bf_lo(unsigned int u) { return __uint_as_float(u << 16); }
static __device__ __forceinline__ float bf_hi(unsigned int u) { return __uint_as_float(u & 0xffff0000u); }
static __device__ __forceinline__ unsigned short f2bf(float f) {
    __hip_bfloat16 h = __float2bfloat16(f);
    return *(unsigned short*)&h;
}
static __device__ __forceinline__ unsigned int pack2(float a, float b) {
    return (unsigned int)f2bf(a) | ((unsigned int)f2bf(b) << 16);
}
static __device__ __forceinline__ unsigned short f2h_bits(float f) {
    union { __half h; unsigned short u; } c; c.h = __float2half_rn(f); return c.u;
}
static __device__ __forceinline__ float h_bits2f(unsigned short u) {
    union { __half h; unsigned short u; } c; c.u = u; return __half2float(c.h);
}

// ================= prep: (dst,src-tile) hist(+rank) + pack W + zero epay ==========
// block ranges: [0,3125) hist | [3125,3413) pack | [3413,4341) zero
__global__ void prep_kernel(const int* __restrict__ src, const int* __restrict__ dst,
                            int* __restrict__ counts2,
                            int* __restrict__ rank,
                            const float* __restrict__ W1, const float* __restrict__ W2,
                            const float* __restrict__ W3, const float* __restrict__ Wd1,
                            const float* __restrict__ Wd2,
                            unsigned short* __restrict__ P1, unsigned short* __restrict__ P2,
                            unsigned short* __restrict__ P3, unsigned short* __restrict__ Pd1,
                            unsigned short* __restrict__ Pd2,
                            unsigned int* __restrict__ epay) {
    int b = blockIdx.x;
    if (b < 3125) {                               // hist over (dst, src-tile), capture rank
        int e = b * 256 + threadIdx.x;
        int d = dst[e], s = src[e];
        int t = s / TILE_N;                       // 0..7
        rank[e] = atomicAdd(&counts2[d * 8 + t], 1);
    } else if (b < 3413) {                        // pack weights
        int idx = (b - 3125) * 256 + threadIdx.x;
        if (idx < 4 * 16384) {
            int which = idx >> 14;
            int r = idx & 16383;
            const float* W = (which == 0) ? W1 : (which == 1) ? W2 : (which == 2) ? W3 : Wd1;
            unsigned short* P = (which == 0) ? P1 : (which == 1) ? P2 : (which == 2) ? P3 : Pd1;
            int j = r & 7, lane = (r >> 3) & 63, t = r >> 9;
            int nb = t & 7, kb = t >> 3;          // NB=8
            int k = kb * 32 + ((lane >> 4) << 3) + j;
            int n = nb * 16 + (lane & 15);
            P[r] = f2bf(W[(size_t)k * 128 + n]);
        } else {
            int r = idx - 65536;
            if (r < 8192) {
                int j = r & 7, lane = (r >> 3) & 63, t = r >> 9;
                int nb = t & 3, kb = t >> 2;      // NB=4
                int k = kb * 32 + ((lane >> 4) << 3) + j;
                int n = nb * 16 + (lane & 15);
                Pd2[r] = f2bf(Wd2[(size_t)k * 64 + n]);
            }
        }
    } else {                                      // zero epay: 928 blocks x 1024 uints
        int i = (b - 3413) * 256 + threadIdx.x;
        *(uint4*)(epay + (size_t)i * 4) = make_uint4(0, 0, 0, 0);
    }
}

// ================= CSR scans (row degree padded to multiple of 4) =================
// scan1: per-row 8-wide exclusive bucket scan (in place in counts2), degree = sum;
// then the usual block-level padded-degree prefix.
__global__ void __launch_bounds__(256) scan1_kernel(int* __restrict__ counts2,
                                                    int* __restrict__ eblk,
                                                    int* __restrict__ bsum,
                                                    float* __restrict__ dinv) {
    __shared__ int ws[4];
    int i = blockIdx.x * 256 + threadIdx.x;
    int deg = 0;
    if (i < N_NODES) {
        int* c = counts2 + (size_t)i * 8;
        uint4 a = *(uint4*)c;
        uint4 bq = *(uint4*)(c + 4);
        int run = 0, tv;
        tv = a.x;  a.x  = run; run += tv;
        tv = a.y;  a.y  = run; run += tv;
        tv = a.z;  a.z  = run; run += tv;
        tv = a.w;  a.w  = run; run += tv;
        tv = bq.x; bq.x = run; run += tv;
        tv = bq.y; bq.y = run; run += tv;
        tv = bq.z; bq.z = run; run += tv;
        tv = bq.w; bq.w = run; run += tv;
        deg = run;
        *(uint4*)c = a;
        *(uint4*)(c + 4) = bq;
        dinv[i] = rsqrtf((float)deg + 1.0f);
    }
    int vp = (deg + 3) & ~3;                      // padded degree
    int lane = threadIdx.x & 63, w = threadIdx.x >> 6;
    int x = vp;
    #pragma unroll
    for (int off = 1; off < 64; off <<= 1) {
        int t = __shfl_up(x, off, 64);
        if (lane >= off) x += t;
    }
    if (lane == 63) ws[w] = x;
    __syncthreads();
    if (threadIdx.x == 0) {
        int run = 0;
        #pragma unroll
        for (int k = 0; k < 4; ++k) { int t = ws[k]; ws[k] = run; run += t; }
        bsum[blockIdx.x] = run;
    }
    __syncthreads();
    if (i < N_NODES) eblk[i] = x - vp + ws[w];
}

// merged scan2+scan3: every block redundantly scans the 196 block sums,
// picks its own exclusive offset, adds to per-element prefixes.
__global__ void __launch_bounds__(256) scanB_kernel(const int* __restrict__ eblk,
                                                    const int* __restrict__ bsum,
                                                    int* __restrict__ rowptr) {
    __shared__ int ws[4];
    __shared__ int sbo;
    int i = threadIdx.x;
    int v = (i < NBLK) ? bsum[i] : 0;
    int lane = i & 63, w = i >> 6;
    int x = v;
    #pragma unroll
    for (int off = 1; off < 64; off <<= 1) {
        int t = __shfl_up(x, off, 64);
        if (lane >= off) x += t;
    }
    if (lane == 63) ws[w] = x;
    __syncthreads();
    if (i == 0) {
        int run = 0;
        #pragma unroll
        for (int k = 0; k < 4; ++k) { int t = ws[k]; ws[k] = run; run += t; }
    }
    __syncthreads();
    int excl = x - v + ws[w];
    if (i == (int)blockIdx.x) sbo = excl;
    if (blockIdx.x == 0 && i == NBLK - 1) rowptr[N_NODES] = excl + v;
    __syncthreads();
    int g = blockIdx.x * 256 + threadIdx.x;
    if (g < N_NODES) rowptr[g] = eblk[g] + sbo;
}

// ================= heterogeneous: XW1 matmul + csr fill (tile-ordered) ============
__global__ void __launch_bounds__(256) fill_mm_kernel(
        const float* __restrict__ x, const unsigned short* __restrict__ P1,
        unsigned short* __restrict__ XW1,
        const int* __restrict__ src, const int* __restrict__ dst,
        const float* __restrict__ dinv,
        const int* __restrict__ rowptr, const int* __restrict__ counts2,
        const int* __restrict__ rank,
        unsigned int* __restrict__ epay) {
    int b = blockIdx.x;
    if (b < MM_BLKS) {
        const int lane = threadIdx.x & 63;
        const int wave = threadIdx.x >> 6;
        const int wid  = b * 4 + wave;
        if (wid * 16 >= N_NODES) return;          // exact: 3125 waves used
        const int node = wid * 16 + (lane & 15);
        const int quad = lane >> 4;
        f32x4 acc[8];
        #pragma unroll
        for (int nb = 0; nb < 8; ++nb) acc[nb] = (f32x4){0.f, 0.f, 0.f, 0.f};
        #pragma unroll
        for (int kb = 0; kb < 4; ++kb) {
            const float* p = x + (size_t)node * 128 + kb * 32 + quad * 8;
            float4 lo = *(const float4*)p;
            float4 hi = *(const float4*)(p + 4);
            union { bf16x8 v; unsigned int u[4]; } tmp;
            tmp.u[0] = pack2(lo.x, lo.y); tmp.u[1] = pack2(lo.z, lo.w);
            tmp.u[2] = pack2(hi.x, hi.y); tmp.u[3] = pack2(hi.z, hi.w);
            #pragma unroll
            for (int nb = 0; nb < 8; ++nb) {
                bf16x8 wf = *(const bf16x8*)(P1 + ((size_t)(kb * 8 + nb) * 64 + lane) * 8);
                acc[nb] = __builtin_amdgcn_mfma_f32_16x16x32_bf16(wf, tmp.v, acc[nb], 0, 0, 0);
            }
        }
        #pragma unroll
        for (int nb = 0; nb < 8; ++nb) {
            int ch = nb * 16 + quad * 4;
            uint2 o;
            o.x = pack2(acc[nb][0], acc[nb][1]);
            o.y = pack2(acc[nb][2], acc[nb][3]);
            *(uint2*)(XW1 + (size_t)node * C_H + ch) = o;
        }
    } else {
        int e = (b - MM_BLKS) * 256 + threadIdx.x;
        if (e < N_EDGES) {
            int d = dst[e], s = src[e];
            int t = s / TILE_N;
            int pos = rowptr[d] + counts2[d * 8 + t] + rank[e];
            float nrm = dinv[s] * dinv[d];
            epay[pos] = (unsigned int)s | ((unsigned int)f2h_bits(nrm) << 16);
        }
    }
}

// ================= layer 1: pure gather(XW1) + bias + relu -> bf16 =================
__global__ void __launch_bounds__(256) gather1_kernel(
        const int* __restrict__ rowptr,
        const unsigned int* __restrict__ epay,
        const float* __restrict__ dinv,
        const unsigned short* __restrict__ hin,
        const float* __restrict__ bias,
        unsigned short* __restrict__ out) {
    int t    = blockIdx.x * 256 + threadIdx.x;
    int node = t >> 4;
    int c8   = (t & 15) << 3;

    float di = dinv[node], dii = di * di;
    uint4 raw = *(const uint4*)(hin + (size_t)node * C_H + c8);
    float a0 = bf_lo(raw.x) * dii, a1 = bf_hi(raw.x) * dii;
    float a2 = bf_lo(raw.y) * dii, a3 = bf_hi(raw.y) * dii;
    float a4 = bf_lo(raw.z) * dii, a5 = bf_hi(raw.z) * dii;
    float a6 = bf_lo(raw.w) * dii, a7 = bf_hi(raw.w) * dii;
    int beg = rowptr[node], end = rowptr[node + 1];
    int p = beg;
    for (; p + 8 <= end; p += 8) {
        uint4 ev0 = *(const uint4*)(epay + p);
        uint4 ev1 = *(const uint4*)(epay + p + 4);
        unsigned int ee[8] = {ev0.x, ev0.y, ev0.z, ev0.w, ev1.x, ev1.y, ev1.z, ev1.w};
        uint4 rv[8];
        #pragma unroll
        for (int j = 0; j < 8; ++j)
            rv[j] = *(const uint4*)(hin + (size_t)(ee[j] & 0xffffu) * C_H + c8);
        #pragma unroll
        for (int j = 0; j < 8; ++j) {
            float nm = h_bits2f((unsigned short)(ee[j] >> 16));
            a0 = fmaf(bf_lo(rv[j].x), nm, a0); a1 = fmaf(bf_hi(rv[j].x), nm, a1);
            a2 = fmaf(bf_lo(rv[j].y), nm, a2); a3 = fmaf(bf_hi(rv[j].y), nm, a3);
            a4 = fmaf(bf_lo(rv[j].z), nm, a4); a5 = fmaf(bf_hi(rv[j].z), nm, a5);
            a6 = fmaf(bf_lo(rv[j].w), nm, a6); a7 = fmaf(bf_hi(rv[j].w), nm, a7);
        }
    }
    if (p < end) {
        uint4 ev = *(const uint4*)(epay + p);
        unsigned int ee[4] = {ev.x, ev.y, ev.z, ev.w};
        uint4 rv[4];
        #pragma unroll
        for (int j = 0; j < 4; ++j)
            rv[j] = *(const uint4*)(hin + (size_t)(ee[j] & 0xffffu) * C_H + c8);
        #pragma unroll
        for (int j = 0; j < 4; ++j) {
            float nm = h_bits2f((unsigned short)(ee[j] >> 16));
            a0 = fmaf(bf_lo(rv[j].x), nm, a0); a1 = fmaf(bf_hi(rv[j].x), nm, a1);
            a2 = fmaf(bf_lo(rv[j].y), nm, a2); a3 = fmaf(bf_hi(rv[j].y), nm, a3);
            a4 = fmaf(bf_lo(rv[j].z), nm, a4); a5 = fmaf(bf_hi(rv[j].z), nm, a5);
            a6 = fmaf(bf_lo(rv[j].w), nm, a6); a7 = fmaf(bf_hi(rv[j].w), nm, a7);
        }
    }
    float4 ba = *(const float4*)(bias + c8);
    float4 bb = *(const float4*)(bias + c8 + 4);
    a0 = fmaxf(a0 + ba.x, 0.f); a1 = fmaxf(a1 + ba.y, 0.f);
    a2 = fmaxf(a2 + ba.z, 0.f); a3 = fmaxf(a3 + ba.w, 0.f);
    a4 = fmaxf(a4 + bb.x, 0.f); a5 = fmaxf(a5 + bb.y, 0.f);
    a6 = fmaxf(a6 + bb.z, 0.f); a7 = fmaxf(a7 + bb.w, 0.f);
    uint4 o;
    o.x = pack2(a0, a1); o.y = pack2(a2, a3);
    o.z = pack2(a4, a5); o.w = pack2(a6, a7);
    *(uint4*)(out + (size_t)node * C_H + c8) = o;
}

// ================= fused layer: gather(A·H) -> LDS tile -> MFMA chain =================
template <bool FINAL>
__global__ void __launch_bounds__(256) fused_layer_kernel(
        const int* __restrict__ rowptr,
        const unsigned int* __restrict__ epay,
        const float* __restrict__ dinv,
        const unsigned short* __restrict__ hin,
        const unsigned short* __restrict__ Wp,
        const float* __restrict__ bias,
        const unsigned short* __restrict__ Wd1p,
        const float* __restrict__ bd1,
        const unsigned short* __restrict__ Wd2p,
        const float* __restrict__ bd2,
        unsigned short* __restrict__ out_b,
        float* __restrict__ out_f) {
    __shared__ unsigned short sG[16 * TSTRIDE];
    const int t = threadIdx.x;

    // ---- phase A: gather agg row into LDS tile, 8 edges in flight ----
    {
        int nl = t >> 4, c8 = (t & 15) << 3;
        int node = blockIdx.x * 16 + nl;
        float di = dinv[node], dii = di * di;
        uint4 raw = *(const uint4*)(hin + (size_t)node * C_H + c8);
        float a0 = bf_lo(raw.x) * dii, a1 = bf_hi(raw.x) * dii;
        float a2 = bf_lo(raw.y) * dii, a3 = bf_hi(raw.y) * dii;
        float a4 = bf_lo(raw.z) * dii, a5 = bf_hi(raw.z) * dii;
        float a6 = bf_lo(raw.w) * dii, a7 = bf_hi(raw.w) * dii;
        int beg = rowptr[node], end = rowptr[node + 1];
        int p = beg;
        for (; p + 8 <= end; p += 8) {
            uint4 ev0 = *(const uint4*)(epay + p);
            uint4 ev1 = *(const uint4*)(epay + p + 4);
            unsigned int ee[8] = {ev0.x, ev0.y, ev0.z, ev0.w, ev1.x, ev1.y, ev1.z, ev1.w};
            uint4 rv[8];
            #pragma unroll
            for (int j = 0; j < 8; ++j)
                rv[j] = *(const uint4*)(hin + (size_t)(ee[j] & 0xffffu) * C_H + c8);
            #pragma unroll
            for (int j = 0; j < 8; ++j) {
                float nm = h_bits2f((unsigned short)(ee[j] >> 16));
                a0 = fmaf(bf_lo(rv[j].x), nm, a0); a1 = fmaf(bf_hi(rv[j].x), nm, a1);
                a2 = fmaf(bf_lo(rv[j].y), nm, a2); a3 = fmaf(bf_hi(rv[j].y), nm, a3);
                a4 = fmaf(bf_lo(rv[j].z), nm, a4); a5 = fmaf(bf_hi(rv[j].z), nm, a5);
                a6 = fmaf(bf_lo(rv[j].w), nm, a6); a7 = fmaf(bf_hi(rv[j].w), nm, a7);
            }
        }
        if (p < end) {
            uint4 ev = *(const uint4*)(epay + p);
            unsigned int ee[4] = {ev.x, ev.y, ev.z, ev.w};
            uint4 rv[4];
            #pragma unroll
            for (int j = 0; j < 4; ++j)
                rv[j] = *(const uint4*)(hin + (size_t)(ee[j] & 0xffffu) * C_H + c8);
            #pragma unroll
            for (int j = 0; j < 4; ++j) {
                float nm = h_bits2f((unsigned short)(ee[j] >> 16));
                a0 = fmaf(bf_lo(rv[j].x), nm, a0); a1 = fmaf(bf_hi(rv[j].x), nm, a1);
                a2 = fmaf(bf_lo(rv[j].y), nm, a2); a3 = fmaf(bf_hi(rv[j].y), nm, a3);
                a4 = fmaf(bf_lo(rv[j].z), nm, a4); a5 = fmaf(bf_hi(rv[j].z), nm, a5);
                a6 = fmaf(bf_lo(rv[j].w), nm, a6); a7 = fmaf(bf_hi(rv[j].w), nm, a7);
            }
        }
        uint4 o;
        o.x = pack2(a0, a1); o.y = pack2(a2, a3);
        o.z = pack2(a4, a5); o.w = pack2(a6, a7);
        *(uint4*)(sG + nl * TSTRIDE + c8) = o;
    }
    __syncthreads();

    const int lane = t & 63, wave = t >> 6, quad = lane >> 4, row = lane & 15;
    const int node = blockIdx.x * 16 + row;

    // ---- mm1: tile @ Wp (COUT=128), bias+relu ----
    f32x4 acc0 = (f32x4){0.f, 0.f, 0.f, 0.f};
    f32x4 acc1 = (f32x4){0.f, 0.f, 0.f, 0.f};
    const int nb0 = 2 * wave, nb1 = 2 * wave + 1;
    #pragma unroll
    for (int kb = 0; kb < 4; ++kb) {
        bf16x8 hf = *(const bf16x8*)(sG + row * TSTRIDE + kb * 32 + quad * 8);
        bf16x8 wf0 = *(const bf16x8*)(Wp + ((size_t)(kb * 8 + nb0) * 64 + lane) * 8);
        bf16x8 wf1 = *(const bf16x8*)(Wp + ((size_t)(kb * 8 + nb1) * 64 + lane) * 8);
        acc0 = __builtin_amdgcn_mfma_f32_16x16x32_bf16(wf0, hf, acc0, 0, 0, 0);
        acc1 = __builtin_amdgcn_mfma_f32_16x16x32_bf16(wf1, hf, acc1, 0, 0, 0);
    }
    float4 ba0 = *(const float4*)(bias + nb0 * 16 + quad * 4);
    float4 ba1 = *(const float4*)(bias + nb1 * 16 + quad * 4);
    float v00 = fmaxf(acc0[0] + ba0.x, 0.f), v01 = fmaxf(acc0[1] + ba0.y, 0.f);
    float v02 = fmaxf(acc0[2] + ba0.z, 0.f), v03 = fmaxf(acc0[3] + ba0.w, 0.f);
    float v10 = fmaxf(acc1[0] + ba1.x, 0.f), v11 = fmaxf(acc1[1] + ba1.y, 0.f);
    float v12 = fmaxf(acc1[2] + ba1.z, 0.f), v13 = fmaxf(acc1[3] + ba1.w, 0.f);

    if (!FINAL) {
        uint2 o0, o1;
        o0.x = pack2(v00, v01); o0.y = pack2(v02, v03);
        o1.x = pack2(v10, v11); o1.y = pack2(v12, v13);
        *(uint2*)(out_b + (size_t)node * C_H + nb0 * 16 + quad * 4) = o0;
        *(uint2*)(out_b + (size_t)node * C_H + nb1 * 16 + quad * 4) = o1;
        return;
    }

    // ---- FINAL: H3 -> tile -> Wd1 -> tile -> Wd2 -> sigmoid -> out_f ----
    __syncthreads();
    {
        uint2 o0, o1;
        o0.x = pack2(v00, v01); o0.y = pack2(v02, v03);
        o1.x = pack2(v10, v11); o1.y = pack2(v12, v13);
        *(uint2*)(sG + row * TSTRIDE + nb0 * 16 + quad * 4) = o0;
        *(uint2*)(sG + row * TSTRIDE + nb1 * 16 + quad * 4) = o1;
    }
    __syncthreads();

    acc0 = (f32x4){0.f, 0.f, 0.f, 0.f};
    acc1 = (f32x4){0.f, 0.f, 0.f, 0.f};
    #pragma unroll
    for (int kb = 0; kb < 4; ++kb) {
        bf16x8 hf = *(const bf16x8*)(sG + row * TSTRIDE + kb * 32 + quad * 8);
        bf16x8 wf0 = *(const bf16x8*)(Wd1p + ((size_t)(kb * 8 + nb0) * 64 + lane) * 8);
        bf16x8 wf1 = *(const bf16x8*)(Wd1p + ((size_t)(kb * 8 + nb1) * 64 + lane) * 8);
        acc0 = __builtin_amdgcn_mfma_f32_16x16x32_bf16(wf0, hf, acc0, 0, 0, 0);
        acc1 = __builtin_amdgcn_mfma_f32_16x16x32_bf16(wf1, hf, acc1, 0, 0, 0);
    }
    ba0 = *(const float4*)(bd1 + nb0 * 16 + quad * 4);
    ba1 = *(const float4*)(bd1 + nb1 * 16 + quad * 4);
    v00 = fmaxf(acc0[0] + ba0.x, 0.f); v01 = fmaxf(acc0[1] + ba0.y, 0.f);
    v02 = fmaxf(acc0[2] + ba0.z, 0.f); v03 = fmaxf(acc0[3] + ba0.w, 0.f);
    v10 = fmaxf(acc1[0] + ba1.x, 0.f); v11 = fmaxf(acc1[1] + ba1.y, 0.f);
    v12 = fmaxf(acc1[2] + ba1.z, 0.f); v13 = fmaxf(acc1[3] + ba1.w, 0.f);
    __syncthreads();
    {
        uint2 o0, o1;
        o0.x = pack2(v00, v01); o0.y = pack2(v02, v03);
        o1.x = pack2(v10, v11); o1.y = pack2(v12, v13);
        *(uint2*)(sG + row * TSTRIDE + nb0 * 16 + quad * 4) = o0;
        *(uint2*)(sG + row * TSTRIDE + nb1 * 16 + quad * 4) = o1;
    }
    __syncthreads();

    f32x4 acc = (f32x4){0.f, 0.f, 0.f, 0.f};
    #pragma unroll
    for (int kb = 0; kb < 4; ++kb) {
        bf16x8 hf = *(const bf16x8*)(sG + row * TSTRIDE + kb * 32 + quad * 8);
        bf16x8 wf = *(const bf16x8*)(Wd2p + ((size_t)(kb * 4 + wave) * 64 + lane) * 8);
        acc = __builtin_amdgcn_mfma_f32_16x16x32_bf16(wf, hf, acc, 0, 0, 0);
    }
    int ch = wave * 16 + quad * 4;
    float4 b4 = *(const float4*)(bd2 + ch);
    float4 r;
    r.x = 1.f / (1.f + expf(-(acc[0] + b4.x)));
    r.y = 1.f / (1.f + expf(-(acc[1] + b4.y)));
    r.z = 1.f / (1.f + expf(-(acc[2] + b4.z)));
    r.w = 1.f / (1.f + expf(-(acc[3] + b4.w)));
    *(float4*)(out_f + (size_t)node * C_OUT + ch) = r;
}

extern "C" void kernel_launch(void* const* d_in, const int* in_sizes, int n_in,
                              void* d_out, int out_size, void* d_ws, size_t ws_size,
                              hipStream_t stream) {
    const float* x   = (const float*)d_in[0];
    const int*   ei  = (const int*)d_in[1];
    const float* W1  = (const float*)d_in[2];
    const float* b1  = (const float*)d_in[3];
    const float* W2  = (const float*)d_in[4];
    const float* b2  = (const float*)d_in[5];
    const float* W3  = (const float*)d_in[6];
    const float* b3  = (const float*)d_in[7];
    const float* Wd1 = (const float*)d_in[8];
    const float* bd1 = (const float*)d_in[9];
    const float* Wd2 = (const float*)d_in[10];
    const float* bd2 = (const float*)d_in[11];

    const int* src = ei;
    const int* dst = ei + N_EDGES;

    char* base = (char*)d_ws;
    size_t off = 0;
    auto alloc = [&](size_t bytes) { char* p = base + off; off += (bytes + 255) & ~size_t(255); return p; };
    int*            counts2 = (int*)alloc((size_t)N_NODES * 8 * 4);   // (dst, src-tile) hist -> bucket offsets
    unsigned int*   epay   = (unsigned int*)alloc((size_t)E_PAD * 4);
    int*            rank   = (int*)alloc((size_t)N_EDGES * 4);
    float*          dinv   = (float*)alloc(N_NODES * 4);
    int*            rowptr = (int*)alloc((N_NODES + 1) * 4);
    int*            eblk   = (int*)alloc(N_NODES * 4);
    int*            bsum   = (int*)alloc(256 * 4);
    unsigned short* XW1    = (unsigned short*)alloc((size_t)N_NODES * C_H * 2);
    unsigned short* bufA   = (unsigned short*)alloc((size_t)N_NODES * C_H * 2);
    unsigned short* bufB   = (unsigned short*)alloc((size_t)N_NODES * C_H * 2);
    unsigned short* P1     = (unsigned short*)alloc(128 * 128 * 2);
    unsigned short* P2     = (unsigned short*)alloc(128 * 128 * 2);
    unsigned short* P3     = (unsigned short*)alloc(128 * 128 * 2);
    unsigned short* Pd1    = (unsigned short*)alloc(128 * 128 * 2);
    unsigned short* Pd2    = (unsigned short*)alloc(128 * 64 * 2);

    const int T = 256;
    dim3 blk(T);
    dim3 gN((N_NODES + T - 1) / T);            // 196
    dim3 gPrep(3125 + 288 + 928);              // hist + pack + zero
    dim3 gFillMM(MM_BLKS + 3125);              // mm + fill
    dim3 gFused(N_NODES / 16);                 // 3125, exact

    hipMemsetAsync(counts2, 0, (size_t)N_NODES * 8 * 4, stream);
    prep_kernel<<<gPrep, blk, 0, stream>>>(src, dst, counts2, rank,
                                           W1, W2, W3, Wd1, Wd2,
                                           P1, P2, P3, Pd1, Pd2, epay);
    scan1_kernel<<<gN, blk, 0, stream>>>(counts2, eblk, bsum, dinv);
    scanB_kernel<<<gN, blk, 0, stream>>>(eblk, bsum, rowptr);
    fill_mm_kernel<<<gFillMM, blk, 0, stream>>>(x, P1, XW1, src, dst, dinv,
                                                rowptr, counts2, rank, epay);

    // ---- layer 1: relu(agg(XW1) + b1) -> bufA (pure gather, tile-ordered edges) ----
    gather1_kernel<<<gFused, blk, 0, stream>>>(rowptr, epay, dinv, XW1, b1, bufA);
    // ---- layer 2 ----
    fused_layer_kernel<false><<<gFused, blk, 0, stream>>>(
        rowptr, epay, dinv, bufA, P2, b2, nullptr, nullptr, nullptr, nullptr, bufB, nullptr);
    // ---- layer 3 + dense head ----
    fused_layer_kernel<true><<<gFused, blk, 0, stream>>>(
        rowptr, epay, dinv, bufB, P3, b3, Pd1, bd1, Pd2, bd2, nullptr, (float*)d_out);
}